// Round 1
// baseline (270.029 us; speedup 1.0000x reference)
//
#include <hip/hip_runtime.h>
#include <hip/hip_bf16.h>

// SerializedEmbedding: out[b,s,:] = weight[indices[b,s], :]
// indices: (8, 2048) int -> 16384 tokens
// weight:  (50304, 1024) fp32
// out:     (8, 2048, 1024) fp32
//
// One block per token; 256 threads copy the 1024-float row as float4.

#define EMB_DIM 1024
#define VEC_PER_ROW (EMB_DIM / 4)   // 256 float4 per row

__global__ __launch_bounds__(256) void SerializedEmbedding_7121055777167_kernel(
    const int* __restrict__ indices,
    const float* __restrict__ weight,
    float* __restrict__ out,
    int num_tokens)
{
    const int token = blockIdx.x;
    if (token >= num_tokens) return;

    const int row = indices[token];  // all indices in [0, 50304)

    const float4* __restrict__ src =
        reinterpret_cast<const float4*>(weight + (size_t)row * EMB_DIM);
    float4* __restrict__ dst =
        reinterpret_cast<float4*>(out + (size_t)token * EMB_DIM);

    dst[threadIdx.x] = src[threadIdx.x];
}

extern "C" void kernel_launch(void* const* d_in, const int* in_sizes, int n_in,
                              void* d_out, int out_size, void* d_ws, size_t ws_size,
                              hipStream_t stream)
{
    const int*   indices = (const int*)d_in[0];
    const float* weight  = (const float*)d_in[1];
    float*       out     = (float*)d_out;

    const int num_tokens = in_sizes[0];  // 8 * 2048 = 16384

    dim3 grid(num_tokens);
    dim3 block(VEC_PER_ROW);  // 256

    SerializedEmbedding_7121055777167_kernel<<<grid, block, 0, stream>>>(
        indices, weight, out, num_tokens);
}